// Round 1
// baseline (38.970 us; speedup 1.0000x reference)
//
#include <hip/hip_runtime.h>

#define NB 2
#define NQS 1024
#define NKS 1024
#define DD 512
#define HH 32

static __device__ __forceinline__ float fexp2(float x) {
#if __has_builtin(__builtin_amdgcn_exp2f)
  return __builtin_amdgcn_exp2f(x);
#else
  float r; asm("v_exp_f32 %0, %1" : "=v"(r) : "v"(x)); return r;
#endif
}
static __device__ __forceinline__ float frcp(float x) {
#if __has_builtin(__builtin_amdgcn_rcpf)
  return __builtin_amdgcn_rcpf(x);
#else
  float r; asm("v_rcp_f32 %0, %1" : "=v"(r) : "v"(x)); return r;
#endif
}

// Phase 1: project rows through W1.
//   rows [0, NB*NKS):      hk'[r][h] = S * (keys_row . W1[0:D, h])
//   rows [NB*NKS, 4096):   hq'[r][h] = S * (queries_row . W1[D:2D, h] + b1[h])
// S = 2*log2(e) folds the tanh->exp2 scaling so phase 2 does s = hk'+hq'.
__global__ __launch_bounds__(256) void p1_proj(
    const float* __restrict__ keys, const float* __restrict__ queries,
    const float* __restrict__ W1, const float* __restrict__ b1,
    float* __restrict__ hkq) {
  const float S = 2.8853900817779268f;  // 2*log2(e)
  int g = blockIdx.x * 256 + threadIdx.x;
  int h = g & 31, row = g >> 5;
  bool isq = row >= NB * NKS;
  const float* src;
  const float* w1;
  if (!isq) {
    src = keys + (size_t)row * DD;
    w1 = W1;
  } else {
    src = queries + (size_t)(row - NB * NKS) * DD;
    w1 = W1 + (size_t)DD * HH;
  }
  float acc = 0.f;
#pragma unroll 4
  for (int d0 = 0; d0 < DD; d0 += 4) {
    float4 rv = *(const float4*)(src + d0);
    acc = fmaf(rv.x, w1[(d0 + 0) * HH + h], acc);
    acc = fmaf(rv.y, w1[(d0 + 1) * HH + h], acc);
    acc = fmaf(rv.z, w1[(d0 + 2) * HH + h], acc);
    acc = fmaf(rv.w, w1[(d0 + 3) * HH + h], acc);
  }
  if (isq) acc += b1[h];
  hkq[(size_t)row * HH + h] = S * acc;
}

// Phase 2: per 64q x 64k tile, logits = c0 + sum_h (-2*W2[h]) * rcp(exp2(s)+1),
// s = hk'[k][h] + hq'[q][h];  c0 = b2 + sum_h W2[h]  (tanh = 1 - 2/(e+1)).
__global__ __launch_bounds__(256) void p2_score(
    const float* __restrict__ hkq, const float* __restrict__ W2,
    const float* __restrict__ b2, float* __restrict__ out) {
  __shared__ float hkL[64 * 33];  // +1 pad: (kl*33+h)%32 = (kl+h)%32 -> 2-way (free)
  __shared__ float hqL[64 * 32];  // broadcast reads, no pad needed
  const int tid = threadIdx.x;
  const int k0 = blockIdx.x * 64, q0 = blockIdx.y * 64, b = blockIdx.z;
  const float* hk_g = hkq + (size_t)(b * NKS + k0) * HH;
  const float* hq_g = hkq + (size_t)NB * NKS * HH + (size_t)(b * NQS + q0) * HH;
#pragma unroll
  for (int j = 0; j < 2; ++j) {
    int i = j * 1024 + tid * 4;  // 2048 floats per tile, 8 per thread
    float4 v = *(const float4*)(hq_g + i);
    *(float4*)(hqL + i) = v;
    float4 w = *(const float4*)(hk_g + i);
    int r = i >> 5, c = i & 31;
    hkL[r * 33 + c + 0] = w.x;
    hkL[r * 33 + c + 1] = w.y;
    hkL[r * 33 + c + 2] = w.z;
    hkL[r * 33 + c + 3] = w.w;
  }
  // Uniform scalars: c0 = b2 + sum W2; w2n[h] = -2*W2[h] (compiler -> SGPRs).
  float w2n[HH];
  float c0 = b2[0];
#pragma unroll
  for (int h = 0; h < HH; ++h) {
    float w = W2[h];
    c0 += w;
    w2n[h] = -2.f * w;
  }
  __syncthreads();
  const int kl = tid & 63, qg = tid >> 6;  // wave-uniform qg
  float hk2[HH];
#pragma unroll
  for (int h = 0; h < HH; ++h) hk2[h] = hkL[kl * 33 + h];
  float* outp = out + (size_t)(b * NQS + q0 + qg * 16) * NKS + k0 + kl;
  const float* hqrow = hqL + qg * 16 * HH;
  for (int j = 0; j < 16; ++j) {
    float acc = c0;
    const float4* hv4 = (const float4*)(hqrow + (size_t)j * HH);
#pragma unroll
    for (int h0 = 0; h0 < 8; ++h0) {
      float4 hv = hv4[h0];
      float s0 = hk2[h0 * 4 + 0] + hv.x;
      acc = fmaf(w2n[h0 * 4 + 0], frcp(fexp2(s0) + 1.f), acc);
      float s1 = hk2[h0 * 4 + 1] + hv.y;
      acc = fmaf(w2n[h0 * 4 + 1], frcp(fexp2(s1) + 1.f), acc);
      float s2 = hk2[h0 * 4 + 2] + hv.z;
      acc = fmaf(w2n[h0 * 4 + 2], frcp(fexp2(s2) + 1.f), acc);
      float s3 = hk2[h0 * 4 + 3] + hv.w;
      acc = fmaf(w2n[h0 * 4 + 3], frcp(fexp2(s3) + 1.f), acc);
    }
    outp[(size_t)j * NKS] = acc;
  }
}

extern "C" void kernel_launch(void* const* d_in, const int* in_sizes, int n_in,
                              void* d_out, int out_size, void* d_ws, size_t ws_size,
                              hipStream_t stream) {
  const float* keys = (const float*)d_in[0];
  const float* queries = (const float*)d_in[1];
  const float* W1 = (const float*)d_in[2];
  const float* b1 = (const float*)d_in[3];
  const float* W2 = (const float*)d_in[4];
  const float* b2 = (const float*)d_in[5];
  float* out = (float*)d_out;
  float* ws = (float*)d_ws;  // hk' [2048*32] then hq' [2048*32] = 512 KB

  // 4096 rows * 32 h = 131072 threads
  hipLaunchKernelGGL(p1_proj, dim3(512), dim3(256), 0, stream,
                     keys, queries, W1, b1, ws);
  hipLaunchKernelGGL(p2_score, dim3(NKS / 64, NQS / 64, NB), dim3(256), 0, stream,
                     ws, W2, b2, out);
}

// Round 2
// 25.842 us; speedup vs baseline: 1.5081x; 1.5081x over previous
//
#include <hip/hip_runtime.h>

#define NB 2
#define NQS 1024
#define NKS 1024
#define DD 512
#define HH 32
#define NROW (NB * NKS)  // key rows; query rows are the next NB*NQS

static __device__ __forceinline__ float fexp2(float x) {
#if __has_builtin(__builtin_amdgcn_exp2f)
  return __builtin_amdgcn_exp2f(x);
#else
  float r; asm("v_exp_f32 %0, %1" : "=v"(r) : "v"(x)); return r;
#endif
}
static __device__ __forceinline__ float frcp(float x) {
#if __has_builtin(__builtin_amdgcn_rcpf)
  return __builtin_amdgcn_rcpf(x);
#else
  float r; asm("v_rcp_f32 %0, %1" : "=v"(r) : "v"(x)); return r;
#endif
}

// Phase 1: E[row][h] = exp2( S * (row . W1col + (isq ? b1 : 0)) ),  S = 2*log2(e).
// Thread layout per wave: hg = t&7 (4 h each, W1 h-contiguous -> float4),
// dq = (t>>3)&3 (128-d quarter), row = t>>5. Butterfly-reduce over dq.
__global__ __launch_bounds__(256) void p1_proj(
    const float* __restrict__ keys, const float* __restrict__ queries,
    const float* __restrict__ W1, const float* __restrict__ b1,
    float* __restrict__ E) {
  const float S = 2.8853900817779268f;  // 2*log2(e)
  const int tid = threadIdx.x;
  const int hg = tid & 7;
  const int dq = (tid >> 3) & 3;
  const int row = blockIdx.x * 8 + (tid >> 5);
  const bool isq = row >= NROW;
  const float* src = (isq ? queries + (size_t)(row - NROW) * DD
                          : keys + (size_t)row * DD) + dq * 128;
  const float* w1 = W1 + ((size_t)(isq ? DD : 0) + dq * 128) * HH + hg * 4;
  float4 a0 = {0.f, 0.f, 0.f, 0.f}, a1 = {0.f, 0.f, 0.f, 0.f};
#pragma unroll 4
  for (int i = 0; i < 32; ++i) {
    float4 s4 = *(const float4*)(src + i * 4);
    const float* wp = w1 + (size_t)i * 4 * HH;
    float4 w0 = *(const float4*)(wp);
    float4 wv1 = *(const float4*)(wp + HH);
    float4 wv2 = *(const float4*)(wp + 2 * HH);
    float4 wv3 = *(const float4*)(wp + 3 * HH);
    a0.x = fmaf(s4.x, w0.x, a0.x);  a0.y = fmaf(s4.x, w0.y, a0.y);
    a0.z = fmaf(s4.x, w0.z, a0.z);  a0.w = fmaf(s4.x, w0.w, a0.w);
    a1.x = fmaf(s4.y, wv1.x, a1.x); a1.y = fmaf(s4.y, wv1.y, a1.y);
    a1.z = fmaf(s4.y, wv1.z, a1.z); a1.w = fmaf(s4.y, wv1.w, a1.w);
    a0.x = fmaf(s4.z, wv2.x, a0.x); a0.y = fmaf(s4.z, wv2.y, a0.y);
    a0.z = fmaf(s4.z, wv2.z, a0.z); a0.w = fmaf(s4.z, wv2.w, a0.w);
    a1.x = fmaf(s4.w, wv3.x, a1.x); a1.y = fmaf(s4.w, wv3.y, a1.y);
    a1.z = fmaf(s4.w, wv3.z, a1.z); a1.w = fmaf(s4.w, wv3.w, a1.w);
  }
  a0.x += a1.x; a0.y += a1.y; a0.z += a1.z; a0.w += a1.w;
  // butterfly over the 4 dq groups (lane xor 8, 16)
  a0.x += __shfl_xor(a0.x, 8);  a0.y += __shfl_xor(a0.y, 8);
  a0.z += __shfl_xor(a0.z, 8);  a0.w += __shfl_xor(a0.w, 8);
  a0.x += __shfl_xor(a0.x, 16); a0.y += __shfl_xor(a0.y, 16);
  a0.z += __shfl_xor(a0.z, 16); a0.w += __shfl_xor(a0.w, 16);
  if ((tid & 24) == 0) {
    float bx = 0.f, by = 0.f, bz = 0.f, bw = 0.f;
    if (isq) {
      const float4 bb = *(const float4*)(b1 + hg * 4);
      bx = bb.x; by = bb.y; bz = bb.z; bw = bb.w;
    }
    float4 o;
    o.x = fexp2(S * (a0.x + bx));
    o.y = fexp2(S * (a0.y + by));
    o.z = fexp2(S * (a0.z + bz));
    o.w = fexp2(S * (a0.w + bw));
    *(float4*)(E + (size_t)row * HH + hg * 4) = o;
  }
}

// Phase 2: logits = c0 + sum_h (-2*W2[h]) * rcp(Ek[k][h]*Eq[q][h] + 1),
// c0 = b2 + sum_h W2[h].   (tanh(x) = 1 - 2/(exp2(2x*log2e)+1))
__global__ __launch_bounds__(256) void p2_score(
    const float* __restrict__ E, const float* __restrict__ W2,
    const float* __restrict__ b2, float* __restrict__ out) {
  __shared__ float EkL[64 * 33];  // +1 pad: 2-way bank alias (free)
  __shared__ float EqL[64 * 32];  // broadcast reads
  const int tid = threadIdx.x;
  const int k0 = blockIdx.x * 64, q0 = blockIdx.y * 64, b = blockIdx.z;
  const float* Ek_g = E + (size_t)(b * NKS + k0) * HH;
  const float* Eq_g = E + (size_t)NROW * HH + (size_t)(b * NQS + q0) * HH;
#pragma unroll
  for (int j = 0; j < 2; ++j) {
    int i = j * 1024 + tid * 4;
    *(float4*)(EqL + i) = *(const float4*)(Eq_g + i);
    float4 w = *(const float4*)(Ek_g + i);
    int r = i >> 5, c = i & 31;
    EkL[r * 33 + c + 0] = w.x;
    EkL[r * 33 + c + 1] = w.y;
    EkL[r * 33 + c + 2] = w.z;
    EkL[r * 33 + c + 3] = w.w;
  }
  float w2n[HH];
  float c0 = b2[0];
#pragma unroll
  for (int h = 0; h < HH; ++h) {
    float w = W2[h];
    c0 += w;
    w2n[h] = -2.f * w;
  }
  __syncthreads();
  const int kl = tid & 63, qg = tid >> 6;  // wave-uniform qg
  float ek[HH];
#pragma unroll
  for (int h = 0; h < HH; ++h) ek[h] = EkL[kl * 33 + h];
  float* outp = out + (size_t)(b * NQS + q0 + qg * 16) * NKS + k0 + kl;
  const float* eqrow = EqL + qg * 16 * HH;
  for (int j = 0; j < 16; ++j) {
    float acc0 = c0, acc1 = 0.f;
    const float4* e4 = (const float4*)(eqrow + (size_t)j * HH);
#pragma unroll
    for (int h0 = 0; h0 < 8; ++h0) {
      float4 ev = e4[h0];
      acc0 = fmaf(w2n[h0 * 4 + 0], frcp(fmaf(ek[h0 * 4 + 0], ev.x, 1.f)), acc0);
      acc1 = fmaf(w2n[h0 * 4 + 1], frcp(fmaf(ek[h0 * 4 + 1], ev.y, 1.f)), acc1);
      acc0 = fmaf(w2n[h0 * 4 + 2], frcp(fmaf(ek[h0 * 4 + 2], ev.z, 1.f)), acc0);
      acc1 = fmaf(w2n[h0 * 4 + 3], frcp(fmaf(ek[h0 * 4 + 3], ev.w, 1.f)), acc1);
    }
    outp[(size_t)j * NKS] = acc0 + acc1;
  }
}

extern "C" void kernel_launch(void* const* d_in, const int* in_sizes, int n_in,
                              void* d_out, int out_size, void* d_ws, size_t ws_size,
                              hipStream_t stream) {
  const float* keys = (const float*)d_in[0];
  const float* queries = (const float*)d_in[1];
  const float* W1 = (const float*)d_in[2];
  const float* b1 = (const float*)d_in[3];
  const float* W2 = (const float*)d_in[4];
  const float* b2 = (const float*)d_in[5];
  float* out = (float*)d_out;
  float* ws = (float*)d_ws;  // E: [4096 rows][32 h] fp32 = 512 KB

  hipLaunchKernelGGL(p1_proj, dim3(512), dim3(256), 0, stream,
                     keys, queries, W1, b1, ws);
  hipLaunchKernelGGL(p2_score, dim3(NKS / 64, NQS / 64, NB), dim3(256), 0, stream,
                     ws, W2, b2, out);
}

// Round 3
// 22.920 us; speedup vs baseline: 1.7003x; 1.1275x over previous
//
#include <hip/hip_runtime.h>
#include <hip/hip_bf16.h>

#define NB 2
#define NQS 1024
#define NKS 1024
#define DD 512
#define HH 32
#define NKROW (NB * NKS)  // 2048 key rows; query rows follow

typedef __attribute__((ext_vector_type(8))) short bf16x8;
typedef __attribute__((ext_vector_type(4))) float f32x4;

static __device__ __forceinline__ float fexp2(float x) {
#if __has_builtin(__builtin_amdgcn_exp2f)
  return __builtin_amdgcn_exp2f(x);
#else
  float r; asm("v_exp_f32 %0, %1" : "=v"(r) : "v"(x)); return r;
#endif
}
static __device__ __forceinline__ float frcp(float x) {
#if __has_builtin(__builtin_amdgcn_rcpf)
  return __builtin_amdgcn_rcpf(x);
#else
  float r; asm("v_rcp_f32 %0, %1" : "=v"(r) : "v"(x)); return r;
#endif
}

// Phase 1 (MFMA): E[row][h] = exp2(S*(row.W1col + (isq? b1 : 0))), S = 2*log2(e).
// One wave per block, 16 rows per wave, K=512, N=32 (2 n-tiles of 16).
// A-frag: lane l -> row m=l&15, k = s*32 + (l>>4)*8 + j (fp32 load + cvt).
// B-frag: lane l -> col l&15, same k pattern (scalar W1 loads; W1 L2-resident).
// C/D: col = lane&15, row = (lane>>4)*4 + reg (m89-verified).
__global__ __launch_bounds__(64) void p1_proj_mfma(
    const float* __restrict__ keys, const float* __restrict__ queries,
    const float* __restrict__ W1, const float* __restrict__ b1,
    float* __restrict__ E) {
  const float S = 2.8853900817779268f;
  const int l = threadIdx.x;
  const int row0 = blockIdx.x * 16;
  const bool isq = row0 >= NKROW;
  const float* src = isq ? (queries + (size_t)(row0 - NKROW) * DD)
                         : (keys + (size_t)row0 * DD);
  const float* w1 = W1 + (isq ? (size_t)DD * HH : (size_t)0);
  const int m = l & 15, kq = l >> 4;
  f32x4 acc0 = {0.f, 0.f, 0.f, 0.f}, acc1 = {0.f, 0.f, 0.f, 0.f};
  const float* arow = src + (size_t)m * DD + kq * 8;
#pragma unroll 2
  for (int s = 0; s < 16; ++s) {
    const int kb = s * 32 + kq * 8;
    float4 a0 = *(const float4*)(arow + s * 32);
    float4 a1 = *(const float4*)(arow + s * 32 + 4);
    union { bf16x8 v; __hip_bfloat16 e[8]; } af, bf0, bf1;
    af.e[0] = __float2bfloat16(a0.x); af.e[1] = __float2bfloat16(a0.y);
    af.e[2] = __float2bfloat16(a0.z); af.e[3] = __float2bfloat16(a0.w);
    af.e[4] = __float2bfloat16(a1.x); af.e[5] = __float2bfloat16(a1.y);
    af.e[6] = __float2bfloat16(a1.z); af.e[7] = __float2bfloat16(a1.w);
    const float* wk = w1 + (size_t)kb * HH;
#pragma unroll
    for (int j = 0; j < 8; ++j) {
      bf0.e[j] = __float2bfloat16(wk[j * HH + m]);
      bf1.e[j] = __float2bfloat16(wk[j * HH + 16 + m]);
    }
    acc0 = __builtin_amdgcn_mfma_f32_16x16x32_bf16(af.v, bf0.v, acc0, 0, 0, 0);
    acc1 = __builtin_amdgcn_mfma_f32_16x16x32_bf16(af.v, bf1.v, acc1, 0, 0, 0);
  }
  float bias0 = 0.f, bias1 = 0.f;
  if (isq) { bias0 = b1[m]; bias1 = b1[16 + m]; }
#pragma unroll
  for (int r = 0; r < 4; ++r) {
    const int rr = row0 + kq * 4 + r;
    E[(size_t)rr * HH + m]      = fexp2(S * (acc0[r] + bias0));
    E[(size_t)rr * HH + 16 + m] = fexp2(S * (acc1[r] + bias1));
  }
}

// Phase 2: logits = c0 + sum_pairs [c01 + A*eq1 + B*eq0] * rcp((1+ek0*eq0)(1+ek1*eq1))
// with A = w0*ek1, B = w1*ek0, w = -2*W2, c01 = w0+w1, c0 = b2 + sum W2.
// Tile: 64 k x 32 q per block (grid 1024), each wave 8 q rows.
__global__ __launch_bounds__(256) void p2_score(
    const float* __restrict__ E, const float* __restrict__ W2,
    const float* __restrict__ b2, float* __restrict__ out) {
  __shared__ float EkL[64 * 33];  // pad: (kl*33+h)%32=(kl+h)%32 -> 2-way (free)
  __shared__ float EqL[32 * 32];
  const int tid = threadIdx.x;
  const int k0 = blockIdx.x * 64, q0 = blockIdx.y * 32, b = blockIdx.z;
  const float* Ek_g = E + (size_t)(b * NKS + k0) * HH;
  const float* Eq_g = E + (size_t)NKROW * HH + (size_t)(b * NQS + q0) * HH;
  {
    int i = tid * 4;  // Ek: 2048 floats in two rounds of 256 float4s
    float4 w = *(const float4*)(Ek_g + i);
    int r = i >> 5, c = i & 31;
    EkL[r * 33 + c + 0] = w.x; EkL[r * 33 + c + 1] = w.y;
    EkL[r * 33 + c + 2] = w.z; EkL[r * 33 + c + 3] = w.w;
    i += 1024;
    w = *(const float4*)(Ek_g + i);
    r = i >> 5; c = i & 31;
    EkL[r * 33 + c + 0] = w.x; EkL[r * 33 + c + 1] = w.y;
    EkL[r * 33 + c + 2] = w.z; EkL[r * 33 + c + 3] = w.w;
    *(float4*)(EqL + tid * 4) = *(const float4*)(Eq_g + tid * 4);  // 1024 floats
  }
  float c0 = b2[0];
  float w2v[HH];
#pragma unroll
  for (int h = 0; h < HH; ++h) { float w = W2[h]; c0 += w; w2v[h] = -2.f * w; }
  float C01[16];
#pragma unroll
  for (int i = 0; i < 16; ++i) C01[i] = w2v[2 * i] + w2v[2 * i + 1];
  __syncthreads();
  const int kl = tid & 63, qg = tid >> 6;  // wave-uniform qg
  float ek[HH];
#pragma unroll
  for (int h = 0; h < HH; ++h) ek[h] = EkL[kl * 33 + h];
  float Aa[16], Bb[16];
#pragma unroll
  for (int i = 0; i < 16; ++i) {
    Aa[i] = w2v[2 * i] * ek[2 * i + 1];
    Bb[i] = w2v[2 * i + 1] * ek[2 * i];
  }
  float* outp = out + (size_t)(b * NQS + q0 + qg * 8) * NKS + k0 + kl;
  const float* eqrow = EqL + qg * 8 * HH;
#pragma unroll 2
  for (int j = 0; j < 8; ++j) {
    float acc0 = c0, acc1 = 0.f;
    const float4* e4 = (const float4*)(eqrow + (size_t)j * HH);
#pragma unroll
    for (int i2 = 0; i2 < 8; ++i2) {
      float4 ev = e4[i2];
      {
        const int i = 2 * i2;
        float da = fmaf(ek[2 * i], ev.x, 1.f);
        float db = fmaf(ek[2 * i + 1], ev.y, 1.f);
        float num = fmaf(Aa[i], ev.y, fmaf(Bb[i], ev.x, C01[i]));
        acc0 = fmaf(num, frcp(da * db), acc0);
      }
      {
        const int i = 2 * i2 + 1;
        float da = fmaf(ek[2 * i], ev.z, 1.f);
        float db = fmaf(ek[2 * i + 1], ev.w, 1.f);
        float num = fmaf(Aa[i], ev.w, fmaf(Bb[i], ev.z, C01[i]));
        acc1 = fmaf(num, frcp(da * db), acc1);
      }
    }
    outp[(size_t)j * NKS] = acc0 + acc1;
  }
}

extern "C" void kernel_launch(void* const* d_in, const int* in_sizes, int n_in,
                              void* d_out, int out_size, void* d_ws, size_t ws_size,
                              hipStream_t stream) {
  const float* keys = (const float*)d_in[0];
  const float* queries = (const float*)d_in[1];
  const float* W1 = (const float*)d_in[2];
  const float* b1 = (const float*)d_in[3];
  const float* W2 = (const float*)d_in[4];
  const float* b2 = (const float*)d_in[5];
  float* out = (float*)d_out;
  float* ws = (float*)d_ws;  // E: [4096][32] fp32 = 512 KB

  hipLaunchKernelGGL(p1_proj_mfma, dim3(256), dim3(64), 0, stream,
                     keys, queries, W1, b1, ws);
  hipLaunchKernelGGL(p2_score, dim3(NKS / 64, NQS / 32, NB), dim3(256), 0, stream,
                     ws, W2, b2, out);
}

// Round 4
// 21.183 us; speedup vs baseline: 1.8397x; 1.0820x over previous
//
#include <hip/hip_runtime.h>
#include <hip/hip_bf16.h>

#define NB 2
#define NQS 1024
#define NKS 1024
#define DD 512
#define HH 32
#define NKROW (NB * NKS)  // 2048 key rows; query rows follow in E
#define W1S 34            // LDS stride: conflict-free B-frag reads, even for b32 merge

typedef __attribute__((ext_vector_type(8))) short bf16x8;
typedef __attribute__((ext_vector_type(4))) float f32x4;

static __device__ __forceinline__ float fexp2(float x) {
#if __has_builtin(__builtin_amdgcn_exp2f)
  return __builtin_amdgcn_exp2f(x);
#else
  float r; asm("v_exp_f32 %0, %1" : "=v"(r) : "v"(x)); return r;
#endif
}
static __device__ __forceinline__ float frcp(float x) {
#if __has_builtin(__builtin_amdgcn_rcpf)
  return __builtin_amdgcn_rcpf(x);
#else
  float r; asm("v_rcp_f32 %0, %1" : "=v"(r) : "v"(x)); return r;
#endif
}

// Phase 1 (MFMA, split-K x4): E[row][h] = exp2(S*(row.W1col + (isq? b1 : 0))).
// 256 blocks x 256 thr. Block = 16 rows; wave w owns K-range [w*128, w*128+128).
// W1 half staged to LDS bf16 stride-34 (bank-conflict-free fragment reads).
// A/B k-slot mapping: k = kb + kq*8 + j for both (m89-verified C/D layout).
__global__ __launch_bounds__(256) void p1_proj_mfma(
    const float* __restrict__ keys, const float* __restrict__ queries,
    const float* __restrict__ W1, const float* __restrict__ b1,
    float* __restrict__ E) {
  __shared__ __hip_bfloat16 W1L[DD * W1S];
  __shared__ float red[4 * 2 * 64 * 4];  // [wave][ntile][lane][reg]
  const float S = 2.8853900817779268f;   // 2*log2(e)
  const int tid = threadIdx.x;
  const int row0 = blockIdx.x * 16;
  const bool isq = row0 >= NKROW;
  const float* src = isq ? queries + (size_t)(row0 - NKROW) * DD
                         : keys + (size_t)row0 * DD;
  const float* w1 = W1 + (isq ? (size_t)DD * HH : 0);
  // ---- stage W1 half (16K fp32 -> bf16 LDS), coalesced float4 reads ----
#pragma unroll
  for (int s = 0; s < 16; ++s) {
    const int f = tid + s * 256;
    float4 v = *(const float4*)(w1 + (size_t)f * 4);
    const int k = f >> 3, h0 = (f & 7) * 4;
    __hip_bfloat16* p = &W1L[k * W1S + h0];
    p[0] = __float2bfloat16(v.x); p[1] = __float2bfloat16(v.y);
    p[2] = __float2bfloat16(v.z); p[3] = __float2bfloat16(v.w);
  }
  __syncthreads();
  const int l = tid & 63, w = tid >> 6;
  const int m = l & 15, kq = l >> 4;
  f32x4 acc0 = {0.f, 0.f, 0.f, 0.f}, acc1 = {0.f, 0.f, 0.f, 0.f};
  const float* arow = src + (size_t)m * DD + w * 128 + kq * 8;
  union Frag { bf16x8 v; __hip_bfloat16 e[8]; };
#pragma unroll
  for (int s = 0; s < 4; ++s) {
    const int kb = w * 128 + s * 32;
    float4 a0 = *(const float4*)(arow + s * 32);
    float4 a1 = *(const float4*)(arow + s * 32 + 4);
    Frag af, bf0, bf1;
    af.e[0] = __float2bfloat16(a0.x); af.e[1] = __float2bfloat16(a0.y);
    af.e[2] = __float2bfloat16(a0.z); af.e[3] = __float2bfloat16(a0.w);
    af.e[4] = __float2bfloat16(a1.x); af.e[5] = __float2bfloat16(a1.y);
    af.e[6] = __float2bfloat16(a1.z); af.e[7] = __float2bfloat16(a1.w);
    const __hip_bfloat16* bp = &W1L[(kb + kq * 8) * W1S + m];
#pragma unroll
    for (int j = 0; j < 8; ++j) {
      bf0.e[j] = bp[j * W1S];
      bf1.e[j] = bp[j * W1S + 16];
    }
    acc0 = __builtin_amdgcn_mfma_f32_16x16x32_bf16(af.v, bf0.v, acc0, 0, 0, 0);
    acc1 = __builtin_amdgcn_mfma_f32_16x16x32_bf16(af.v, bf1.v, acc1, 0, 0, 0);
  }
  *(f32x4*)(&red[((w * 2 + 0) * 64 + l) * 4]) = acc0;
  *(f32x4*)(&red[((w * 2 + 1) * 64 + l) * 4]) = acc1;
  __syncthreads();
  // ---- split-K reduce + bias + exp2: 512 outputs, 2 per thread ----
#pragma unroll
  for (int u = 0; u < 2; ++u) {
    const int o = tid + u * 256;
    const int rr = o >> 5, h = o & 31;
    const int t = h >> 4, mm = h & 15;
    const int ll = ((rr >> 2) << 4) | mm, r = rr & 3;
    float sum = red[(0 + t) * 256 + ll * 4 + r] + red[(2 + t) * 256 + ll * 4 + r] +
                red[(4 + t) * 256 + ll * 4 + r] + red[(6 + t) * 256 + ll * 4 + r];
    if (isq) sum += b1[h];
    E[(size_t)(row0 + rr) * HH + h] = fexp2(S * sum);
  }
}

// Phase 2: logits = c0 + sum_pairs [C01 + A*eq1 + B*eq0] * rcp((1+ek0*eq0)(1+ek1*eq1))
// A = w0*ek1, B = w1*ek0, w = -2*W2, c0 = b2 + sum W2. No LDS: ek per-lane from
// global (L2-resident), eq via wave-uniform (readfirstlane) pointer -> s_load.
__global__ __launch_bounds__(256) void p2_score(
    const float* __restrict__ E, const float* __restrict__ W2,
    const float* __restrict__ b2, float* __restrict__ out) {
  const int tid = threadIdx.x;
  const int kl = tid & 63;
  const int qg = __builtin_amdgcn_readfirstlane(tid >> 6);  // wave-uniform
  const int k0 = blockIdx.x * 64, q0 = blockIdx.y * 32, b = blockIdx.z;
  // per-lane ek[32]: 8 coalesced-ish float4 loads (L1/L2 hit after first touch)
  const float* ekp = E + (size_t)(b * NKS + k0 + kl) * HH;
  float ek[HH];
#pragma unroll
  for (int i = 0; i < 8; ++i) {
    float4 v = *(const float4*)(ekp + i * 4);
    ek[i * 4 + 0] = v.x; ek[i * 4 + 1] = v.y;
    ek[i * 4 + 2] = v.z; ek[i * 4 + 3] = v.w;
  }
  float c0 = b2[0];
  float w2v[HH];
#pragma unroll
  for (int h = 0; h < HH; ++h) { float ww = W2[h]; c0 += ww; w2v[h] = -2.f * ww; }
  float Aa[16], Bb[16], C01[16];
#pragma unroll
  for (int i = 0; i < 16; ++i) {
    Aa[i] = w2v[2 * i] * ek[2 * i + 1];
    Bb[i] = w2v[2 * i + 1] * ek[2 * i];
    C01[i] = w2v[2 * i] + w2v[2 * i + 1];
  }
  const float* eqb = E + ((size_t)NKROW + (size_t)b * NQS + q0 + qg * 8) * HH;
  float* outp = out + ((size_t)b * NQS + q0 + qg * 8) * NKS + k0 + kl;
#pragma unroll 2
  for (int j = 0; j < 8; ++j) {
    const float* ej = eqb + (size_t)j * HH;  // uniform -> s_load
    float acc0 = c0, acc1 = 0.f;
#pragma unroll
    for (int i2 = 0; i2 < 8; ++i2) {
      float4 ev = *(const float4*)(ej + i2 * 4);
      {
        const int i = 2 * i2;
        float da = fmaf(ek[2 * i], ev.x, 1.f);
        float db = fmaf(ek[2 * i + 1], ev.y, 1.f);
        float num = fmaf(Aa[i], ev.y, fmaf(Bb[i], ev.x, C01[i]));
        acc0 = fmaf(num, frcp(da * db), acc0);
      }
      {
        const int i = 2 * i2 + 1;
        float da = fmaf(ek[2 * i], ev.z, 1.f);
        float db = fmaf(ek[2 * i + 1], ev.w, 1.f);
        float num = fmaf(Aa[i], ev.w, fmaf(Bb[i], ev.z, C01[i]));
        acc1 = fmaf(num, frcp(da * db), acc1);
      }
    }
    outp[(size_t)j * NKS] = acc0 + acc1;
  }
}

extern "C" void kernel_launch(void* const* d_in, const int* in_sizes, int n_in,
                              void* d_out, int out_size, void* d_ws, size_t ws_size,
                              hipStream_t stream) {
  const float* keys = (const float*)d_in[0];
  const float* queries = (const float*)d_in[1];
  const float* W1 = (const float*)d_in[2];
  const float* b1 = (const float*)d_in[3];
  const float* W2 = (const float*)d_in[4];
  const float* b2 = (const float*)d_in[5];
  float* out = (float*)d_out;
  float* ws = (float*)d_ws;  // E: [4096][32] fp32 = 512 KB

  hipLaunchKernelGGL(p1_proj_mfma, dim3(256), dim3(256), 0, stream,
                     keys, queries, W1, b1, ws);
  hipLaunchKernelGGL(p2_score, dim3(NKS / 64, NQS / 32, NB), dim3(256), 0, stream,
                     ws, W2, b2, out);
}